// Round 4
// baseline (380.877 us; speedup 1.0000x reference)
//
#include <hip/hip_runtime.h>
#include <hip/hip_cooperative_groups.h>
#include <math.h>

namespace cg = cooperative_groups;

// ---------------------------------------------------------------------------
// StatePerturbationEncoder. Primary path: ONE cooperative kernel, 512 blocks
// x 256 threads (2 blocks/CU). Each block owns 64 rows; the 64x256 activation
// tile lives in LDS across all 4 layers (XOR-swizzled, unpadded -> total LDS
// exactly 65536 B, the sharedMemPerBlock limit that killed R3's 66560 B).
// BatchNorm = grid-wide sharded column stats + grid.sync + in-LDS affine.
// Fallback path (if cooperative launch errors): R2's proven 8-kernel pipeline.
// ---------------------------------------------------------------------------

typedef __attribute__((ext_vector_type(8))) short short8;   // 8 x bf16
typedef __attribute__((ext_vector_type(4))) float floatx4;  // MFMA acc

#define DDIM 256

__device__ __forceinline__ unsigned short f2bf(float f) {
    union { float f; unsigned int u; } v; v.f = f;
    unsigned int r = v.u + 0x7fffu + ((v.u >> 16) & 1u);   // RNE
    return (unsigned short)(r >> 16);
}
__device__ __forceinline__ float bf2f(unsigned short u) {
    union { unsigned int i; float f; } v; v.i = ((unsigned int)u) << 16;
    return v.f;
}
__device__ __forceinline__ float gelu_fast(float x) {
    // tanh-approx GELU, branchless (validated R2: absmax 0.023 vs 0.076 thr)
    float z = 0.7978845608f * (x + 0.044715f * x * x * x);
    float e = __expf(2.0f * z);
    float th = 1.0f - 2.0f * __builtin_amdgcn_rcpf(1.0f + e);
    return 0.5f * x * (1.0f + th);
}
__device__ __forceinline__ void load_lds16(const void* g, void* l) {
    __builtin_amdgcn_global_load_lds(
        (__attribute__((address_space(1))) void*)(g),
        (__attribute__((address_space(3))) void*)(l),
        16, 0, 0);
}

// ============================ cooperative path =============================

struct Params {
    const int* ids; const float* table;
    const float* W[4]; const float* b[4];
    const float* g[3]; const float* be[3];
    unsigned short* Wt;   // ws: 4 * 256*256 bf16, W^T as [n][k]
    float* stats;         // ws: 3 layers * 8 shards * (sum[256], sq[256])
    float* out;
};

__global__ __launch_bounds__(256, 2) void fused_encoder(Params p)
{
    // Albs: [64 rows][32 granules of 8 bf16]; granule g of row r at slot
    // g ^ (r&7)  (A-frag b128 reads: <=2 lanes per bank-group).
    __shared__ alignas(16) unsigned short Albs[64 * 256];    // 32768 B
    // Wlds: 4 waves x 2 halves x [64 n][4 granules]; granule q of row n at
    // slot q ^ ((n>>1)&3) (B-frag reads: <=2 lanes per bank-group).
    __shared__ alignas(16) unsigned short Wlds[16384];       // 32768 B
    cg::grid_group grid = cg::this_grid();

    const int tid  = threadIdx.x;
    const int blk  = blockIdx.x;
    const int wave = tid >> 6;
    const int lane = tid & 63;
    const int quad = lane >> 4;
    const int l15  = lane & 15;
    const int wn   = wave;          // wave's 64-col band
    const int row0 = blk * 64;

    // ---------------- prologue ----------------
    for (int it = 0; it < 8; ++it) {        // gather 64 rows -> Albs (bf16)
        const int r   = it * 8 + (tid >> 5);
        const int g   = tid & 31;           // 16B granule = 8 cols
        const int src = p.ids[row0 + r];
        const float4* tp = (const float4*)(p.table + (size_t)src * 256 + g * 8);
        float4 v0 = tp[0], v1 = tp[1];
        union { unsigned short u[8]; uint4 v; } o;
        o.u[0]=f2bf(v0.x); o.u[1]=f2bf(v0.y); o.u[2]=f2bf(v0.z); o.u[3]=f2bf(v0.w);
        o.u[4]=f2bf(v1.x); o.u[5]=f2bf(v1.y); o.u[6]=f2bf(v1.z); o.u[7]=f2bf(v1.w);
        *(uint4*)(Albs + r * 256 + (g ^ (r & 7)) * 8) = o.v;
    }
    {   // transpose+cast 2 columns of one W into Wt (spread over 512 blocks)
        const int j  = blk >> 7;
        const int c0 = (blk & 127) * 2;
        const float* Wj = p.W[j];
        unsigned short* WtJ = p.Wt + ((size_t)j << 16);
        WtJ[(size_t)(c0    ) * 256 + tid] = f2bf(Wj[(size_t)tid * 256 + c0    ]);
        WtJ[(size_t)(c0 + 1) * 256 + tid] = f2bf(Wj[(size_t)tid * 256 + c0 + 1]);
    }
    if (blk < 12) {                         // zero stat shards (12288 floats)
        float* s = p.stats + blk * 1024;
        s[tid] = 0.f; s[tid + 256] = 0.f; s[tid + 512] = 0.f; s[tid + 768] = 0.f;
    }
    grid.sync();

    // ---------------- 4 fused layers ----------------
    for (int layer = 0; layer < 4; ++layer) {
        __syncthreads();   // Albs stable (gather / previous affine)

        const unsigned short* WtL = p.Wt + ((size_t)layer << 16);
        float bias_v[4];
#pragma unroll
        for (int nt = 0; nt < 4; ++nt)
            bias_v[nt] = p.b[layer][wn * 64 + nt * 16 + l15];

        floatx4 acc[4][4];
#pragma unroll
        for (int i = 0; i < 4; ++i)
#pragma unroll
            for (int j = 0; j < 4; ++j)
                acc[i][j] = floatx4{0.f, 0.f, 0.f, 0.f};

        // wave-private staging of Wt[n: wn*64..+64][k: kk*32..+32] (4 KB).
        // DMA dest is lane*16; swizzle by fetching granule (lane&3)^((lane>>3)&3)
        // so physical slot s of row n holds logical granule s^((n>>1)&3).
        auto stage = [&](int kk, int hb) {
            const int q = ((lane & 3) ^ ((lane >> 3) & 3)) * 8;
            const unsigned short* gs = WtL
                + (size_t)(wn * 64 + (lane >> 2)) * 256 + kk * 32 + q;
            unsigned short* ld = Wlds + wn * 4096 + hb * 2048;
            load_lds16(gs,            ld);
            load_lds16(gs + 16 * 256, ld + 512);
            load_lds16(gs + 32 * 256, ld + 1024);
            load_lds16(gs + 48 * 256, ld + 1536);
        };

        stage(0, 0);
        for (int kk = 0; kk < 8; ++kk) {    // K = 256, BK = 32, no barriers
            const int hb = kk & 1;
            if (kk < 7) {
                stage(kk + 1, hb ^ 1);
                __builtin_amdgcn_s_waitcnt(0x0F74);   // vmcnt(4): kk's 4 landed
            } else {
                __builtin_amdgcn_s_waitcnt(0x0F70);   // vmcnt(0)
            }
            short8 af[4], bfr[4];
            const int agp   = ((kk * 4 + quad) ^ (l15 & 7)) * 8;
            const int bslot = (quad ^ ((l15 >> 1) & 3)) * 8;
#pragma unroll
            for (int mt = 0; mt < 4; ++mt)
                af[mt] = *(const short8*)(Albs + (mt * 16 + l15) * 256 + agp);
#pragma unroll
            for (int nt = 0; nt < 4; ++nt)
                bfr[nt] = *(const short8*)(Wlds + wn * 4096 + hb * 2048
                                           + (nt * 16 + l15) * 32 + bslot);
#pragma unroll
            for (int mt = 0; mt < 4; ++mt)
#pragma unroll
                for (int nt = 0; nt < 4; ++nt)
                    acc[mt][nt] = __builtin_amdgcn_mfma_f32_16x16x32_bf16(
                        af[mt], bfr[nt], acc[mt][nt], 0, 0, 0);
        }

        if (layer < 3) {
            __syncthreads();   // all waves done reading Albs before overwrite
            float s1[4] = {0.f, 0.f, 0.f, 0.f};
            float s2[4] = {0.f, 0.f, 0.f, 0.f};
#pragma unroll
            for (int mt = 0; mt < 4; ++mt) {
#pragma unroll
                for (int nt = 0; nt < 4; ++nt) {
                    const int col = wn * 64 + nt * 16 + l15;   // C/D col=lane&15
#pragma unroll
                    for (int i = 0; i < 4; ++i) {
                        const int row = mt * 16 + quad * 4 + i; // row=quad*4+reg
                        float y = gelu_fast(acc[mt][nt][i] + bias_v[nt]);
                        Albs[row * 256 + ((col >> 3) ^ (row & 7)) * 8 + (col & 7)]
                            = f2bf(y);
                        s1[nt] += y; s2[nt] += y * y;
                    }
                }
            }
#pragma unroll
            for (int nt = 0; nt < 4; ++nt) {   // reduce quads (same column)
                s1[nt] += __shfl_xor(s1[nt], 16); s1[nt] += __shfl_xor(s1[nt], 32);
                s2[nt] += __shfl_xor(s2[nt], 16); s2[nt] += __shfl_xor(s2[nt], 32);
            }
            float* sb = p.stats + layer * 4096 + (blk & 7) * 512;  // 8-way shard
            if (quad == 0) {
#pragma unroll
                for (int nt = 0; nt < 4; ++nt) {
                    const int col = wn * 64 + nt * 16 + l15;
                    atomicAdd(&sb[col],       s1[nt]);
                    atomicAdd(&sb[256 + col], s2[nt]);
                }
            }
            grid.sync();   // stats complete device-wide

            // BN affine applied in-place; thread t owns column t
            {
                const float* st = p.stats + layer * 4096;
                float sum = 0.f, sq = 0.f;
#pragma unroll
                for (int s = 0; s < 8; ++s) {
                    sum += st[s * 512 + tid];
                    sq  += st[s * 512 + 256 + tid];
                }
                const float mu  = sum * (1.f / 32768.f);
                const float var = sq * (1.f / 32768.f) - mu * mu;
                const float scl = rsqrtf(var + 1e-5f) * p.g[layer][tid];
                const float shf = p.be[layer][tid] - mu * scl;
                const int gt = tid >> 3, ct = tid & 7;
                for (int r = 0; r < 64; ++r) {
                    const int idx = r * 256 + ((gt ^ (r & 7)) * 8) + ct;
                    Albs[idx] = f2bf(fmaf(bf2f(Albs[idx]), scl, shf));
                }
            }
        } else {
            // final layer: GELU -> fp32 output (no swizzle: global memory)
#pragma unroll
            for (int mt = 0; mt < 4; ++mt) {
                const int rb = row0 + mt * 16 + quad * 4;
#pragma unroll
                for (int nt = 0; nt < 4; ++nt) {
                    const int col = wn * 64 + nt * 16 + l15;
#pragma unroll
                    for (int i = 0; i < 4; ++i)
                        p.out[(size_t)(rb + i) * 256 + col] =
                            gelu_fast(acc[mt][nt][i] + bias_v[nt]);
                }
            }
        }
    }
}

// ======================= fallback path (R2, proven) ========================

__global__ void gather_prep(const int* __restrict__ ids,
                            const float* __restrict__ table,
                            const float* __restrict__ W1,
                            unsigned short* __restrict__ X0,
                            unsigned short* __restrict__ W1t,
                            float* __restrict__ stats)
{
    const int b = blockIdx.x;
    const int t = threadIdx.x;
    if (b < 4096) {
        const int r   = b * 8 + (t >> 5);
        const int lc  = t & 31;
        const int src = ids[r];
        const float4* tp = (const float4*)(table + (size_t)src * DDIM);
        float4 v0 = tp[lc];
        float4 v1 = tp[32 + lc];
        union { unsigned short u[4]; uint2 v; } o0, o1;
        o0.u[0] = f2bf(v0.x); o0.u[1] = f2bf(v0.y);
        o0.u[2] = f2bf(v0.z); o0.u[3] = f2bf(v0.w);
        o1.u[0] = f2bf(v1.x); o1.u[1] = f2bf(v1.y);
        o1.u[2] = f2bf(v1.z); o1.u[3] = f2bf(v1.w);
        *(uint2*)(X0 + (size_t)r * DDIM + lc * 4)       = o0.v;
        *(uint2*)(X0 + (size_t)r * DDIM + 128 + lc * 4) = o1.v;
        if (b == 0) {
            for (int i = t; i < 1536; i += 256) stats[i] = 0.f;
        }
    } else {
        const int n = b - 4096;
        W1t[n * DDIM + t] = f2bf(W1[t * DDIM + n]);
    }
}

template<int WRITE_F32, int DO_STATS>
__global__ __launch_bounds__(256, 2)
void gemm_fused(const unsigned short* __restrict__ A,
                const unsigned short* __restrict__ Bt,
                const float* __restrict__ bias,
                void* __restrict__ outp,
                float* __restrict__ statSum,
                float* __restrict__ statSq)
{
    __shared__ alignas(16) unsigned short As[4096];
    __shared__ alignas(16) unsigned short Bs[4096];
    __shared__ float colsum[128];
    __shared__ float colsq[128];

    const int tid  = threadIdx.x;
    const int wave = tid >> 6;
    const int lane = tid & 63;
    const int quad = lane >> 4;
    const int l15  = lane & 15;
    const int wm   = wave >> 1;
    const int wn   = wave & 1;

    const int m0 = blockIdx.x * 128;
    const int n0 = blockIdx.y * 128;

    const unsigned short* aP0 = A  + (size_t)(m0 +      (tid >> 2)) * DDIM + (tid & 3) * 8;
    const unsigned short* aP1 = A  + (size_t)(m0 + 64 + (tid >> 2)) * DDIM + (tid & 3) * 8;
    const unsigned short* bP0 = Bt + (size_t)(n0 +      (tid >> 2)) * DDIM + (tid & 3) * 8;
    const unsigned short* bP1 = Bt + (size_t)(n0 + 64 + (tid >> 2)) * DDIM + (tid & 3) * 8;
    unsigned short* asD0 = As +        wave * 512;
    unsigned short* asD1 = As + 2048 + wave * 512;
    unsigned short* bsD0 = Bs +        wave * 512;
    unsigned short* bsD1 = Bs + 2048 + wave * 512;

    floatx4 zero = {0.f, 0.f, 0.f, 0.f};
    floatx4 acc[4][4];
#pragma unroll
    for (int i = 0; i < 4; ++i)
#pragma unroll
        for (int j = 0; j < 4; ++j) acc[i][j] = zero;

    float bias_v[4];
#pragma unroll
    for (int nt = 0; nt < 4; ++nt)
        bias_v[nt] = bias[n0 + wn * 64 + nt * 16 + l15];

    for (int kk = 0; kk < 8; ++kk) {
        __syncthreads();
        load_lds16(aP0, asD0);
        load_lds16(aP1, asD1);
        load_lds16(bP0, bsD0);
        load_lds16(bP1, bsD1);
        aP0 += 32; aP1 += 32; bP0 += 32; bP1 += 32;
        __syncthreads();

        short8 af[4], bf[4];
#pragma unroll
        for (int mt = 0; mt < 4; ++mt)
            af[mt] = *(const short8*)(As + (wm * 64 + mt * 16 + l15) * 32 + quad * 8);
#pragma unroll
        for (int nt = 0; nt < 4; ++nt)
            bf[nt] = *(const short8*)(Bs + (wn * 64 + nt * 16 + l15) * 32 + quad * 8);
#pragma unroll
        for (int mt = 0; mt < 4; ++mt)
#pragma unroll
            for (int nt = 0; nt < 4; ++nt)
                acc[mt][nt] = __builtin_amdgcn_mfma_f32_16x16x32_bf16(
                    af[mt], bf[nt], acc[mt][nt], 0, 0, 0);
    }

    float s1[4], s2[4];
#pragma unroll
    for (int nt = 0; nt < 4; ++nt) { s1[nt] = 0.f; s2[nt] = 0.f; }

#pragma unroll
    for (int mt = 0; mt < 4; ++mt) {
        const int rowb = m0 + wm * 64 + mt * 16 + quad * 4;
#pragma unroll
        for (int nt = 0; nt < 4; ++nt) {
            const int col = n0 + wn * 64 + nt * 16 + l15;
#pragma unroll
            for (int i = 0; i < 4; ++i) {
                float y = acc[mt][nt][i] + bias_v[nt];
                y = gelu_fast(y);
                if (WRITE_F32) {
                    ((float*)outp)[(size_t)(rowb + i) * DDIM + col] = y;
                } else {
                    ((unsigned short*)outp)[(size_t)(rowb + i) * DDIM + col] = f2bf(y);
                }
                if (DO_STATS) { s1[nt] += y; s2[nt] += y * y; }
            }
        }
    }

    if (DO_STATS) {
#pragma unroll
        for (int nt = 0; nt < 4; ++nt) {
            s1[nt] += __shfl_xor(s1[nt], 16);
            s1[nt] += __shfl_xor(s1[nt], 32);
            s2[nt] += __shfl_xor(s2[nt], 16);
            s2[nt] += __shfl_xor(s2[nt], 32);
        }
        if (tid < 128) { colsum[tid] = 0.f; colsq[tid] = 0.f; }
        __syncthreads();
        if (quad == 0) {
#pragma unroll
            for (int nt = 0; nt < 4; ++nt) {
                const int c = wn * 64 + nt * 16 + l15;
                atomicAdd(&colsum[c], s1[nt]);
                atomicAdd(&colsq[c], s2[nt]);
            }
        }
        __syncthreads();
        if (tid < 128) {
            atomicAdd(&statSum[n0 + tid], colsum[tid]);
            atomicAdd(&statSq[n0 + tid], colsq[tid]);
        }
    }
}

__global__ void fold_kernel(const float* __restrict__ sum,
                            const float* __restrict__ sq,
                            const float* __restrict__ g,
                            const float* __restrict__ be,
                            const float* __restrict__ W,
                            const float* __restrict__ b,
                            unsigned short* __restrict__ Wt,
                            float* __restrict__ bOut)
{
    __shared__ float sc[256], sh[256], red[4];
    const int t = threadIdx.x;
    const int n = blockIdx.x;
    const float mu  = sum[t] * (1.0f / 32768.0f);
    const float var = sq[t] * (1.0f / 32768.0f) - mu * mu;
    const float scale = rsqrtf(var + 1e-5f) * g[t];
    sc[t] = scale;
    sh[t] = be[t] - mu * scale;
    __syncthreads();
    const float w = W[t * DDIM + n];
    Wt[n * DDIM + t] = f2bf(sc[t] * w);
    float pp = sh[t] * w;
#pragma unroll
    for (int o = 32; o; o >>= 1) pp += __shfl_down(pp, o);
    if ((t & 63) == 0) red[t >> 6] = pp;
    __syncthreads();
    if (t == 0) bOut[n] = b[n] + red[0] + red[1] + red[2] + red[3];
}

// ---------------------------------------------------------------------------
extern "C" void kernel_launch(void* const* d_in, const int* in_sizes, int n_in,
                              void* d_out, int out_size, void* d_ws, size_t ws_size,
                              hipStream_t stream)
{
    const int*   ids   = (const int*)  d_in[0];
    const float* table = (const float*)d_in[1];

    Params prm;
    prm.ids   = ids;
    prm.table = table;
    prm.W[0] = (const float*)d_in[2];  prm.b[0] = (const float*)d_in[3];
    prm.W[1] = (const float*)d_in[4];  prm.b[1] = (const float*)d_in[5];
    prm.W[2] = (const float*)d_in[6];  prm.b[2] = (const float*)d_in[7];
    prm.W[3] = (const float*)d_in[8];  prm.b[3] = (const float*)d_in[9];
    prm.g[0]  = (const float*)d_in[10]; prm.be[0] = (const float*)d_in[11];
    prm.g[1]  = (const float*)d_in[12]; prm.be[1] = (const float*)d_in[13];
    prm.g[2]  = (const float*)d_in[14]; prm.be[2] = (const float*)d_in[15];

    unsigned char* ws = (unsigned char*)d_ws;
    prm.Wt    = (unsigned short*)ws;                    // 524288 B
    prm.stats = (float*)(ws + (size_t)524288);          // 49152 B
    prm.out   = (float*)d_out;

    void* args[] = { &prm };
    hipError_t cerr = hipLaunchCooperativeKernel((const void*)fused_encoder,
                                                 dim3(512), dim3(256), args,
                                                 0, stream);
    if (cerr == hipSuccess) return;

    // ---------------- fallback: proven 8-kernel pipeline (R2) ----------------
    unsigned short* buf0 = (unsigned short*)(ws + (size_t)1048576);
    unsigned short* buf1 = (unsigned short*)(ws + (size_t)1048576 + 16777216);
    unsigned short* W1t  = (unsigned short*)(ws + (size_t)1048576 + 33554432);
    unsigned short* Wf0  = (unsigned short*)(ws + (size_t)1048576 + 33685504);
    unsigned short* Wf1  = (unsigned short*)(ws + (size_t)1048576 + 33816576);
    unsigned short* Wf2  = (unsigned short*)(ws + (size_t)1048576 + 33947648);
    float* bf0 = (float*)(ws + (size_t)1048576 + 34078720);
    float* bf1 = (float*)(ws + (size_t)1048576 + 34079744);
    float* bf2 = (float*)(ws + (size_t)1048576 + 34080768);
    float* stats = (float*)(ws + (size_t)1048576 + 34081792);
    float *sum0 = stats,        *sq0 = stats + 256;
    float *sum1 = stats + 512,  *sq1 = stats + 768;
    float *sum2 = stats + 1024, *sq2 = stats + 1280;

    const float* W1 = prm.W[0];

    gather_prep<<<4352, 256, 0, stream>>>(ids, table, W1, buf0, W1t, stats);

    dim3 ggrid(256, 2);
    gemm_fused<0, 1><<<ggrid, 256, 0, stream>>>(buf0, W1t, prm.b[0], buf1, sum0, sq0);
    fold_kernel<<<256, 256, 0, stream>>>(sum0, sq0, prm.g[0], prm.be[0], prm.W[1], prm.b[1], Wf0, bf0);
    gemm_fused<0, 1><<<ggrid, 256, 0, stream>>>(buf1, Wf0, bf0, buf0, sum1, sq1);
    fold_kernel<<<256, 256, 0, stream>>>(sum1, sq1, prm.g[1], prm.be[1], prm.W[2], prm.b[2], Wf1, bf1);
    gemm_fused<0, 1><<<ggrid, 256, 0, stream>>>(buf0, Wf1, bf1, buf1, sum2, sq2);
    fold_kernel<<<256, 256, 0, stream>>>(sum2, sq2, prm.g[2], prm.be[2], prm.W[3], prm.b[3], Wf2, bf2);
    gemm_fused<1, 0><<<ggrid, 256, 0, stream>>>(buf1, Wf2, bf2, (void*)d_out, nullptr, nullptr);
}

// Round 6
// 182.171 us; speedup vs baseline: 2.0908x; 2.0908x over previous
//
#include <hip/hip_runtime.h>
#include <math.h>

// ---------------------------------------------------------------------------
// StatePerturbationEncoder, R6: multi-kernel, gather fused into GEMM1,
// BN folded into next layer's weights. GEMM = 64m x 256n full-row blocks
// (512 blocks); A panel staged once in LDS (XOR-swizzled); B fragments are
// loaded DIRECTLY from global (Wt is 128 KB -> L1/L2 resident). No manual
// s_waitcnt, no global_load_lds: R5's vmcnt-counting protocol was broken by
// backend VMEM reordering (absmax 1.14) — all hazards are compiler-managed
// here. K-loop has zero barriers; the only barrier is after A staging.
// ---------------------------------------------------------------------------

typedef __attribute__((ext_vector_type(8))) short short8;   // 8 x bf16
typedef __attribute__((ext_vector_type(4))) float floatx4;  // MFMA acc

#define DDIM 256

__device__ __forceinline__ unsigned short f2bf(float f) {
    union { float f; unsigned int u; } v; v.f = f;
    unsigned int r = v.u + 0x7fffu + ((v.u >> 16) & 1u);   // RNE
    return (unsigned short)(r >> 16);
}
__device__ __forceinline__ float gelu_fast(float x) {
    // tanh-approx GELU, branchless (validated: absmax 0.023 vs 0.076 thr)
    float z = 0.7978845608f * (x + 0.044715f * x * x * x);
    float e = __expf(2.0f * z);
    float th = 1.0f - 2.0f * __builtin_amdgcn_rcpf(1.0f + e);
    return 0.5f * x * (1.0f + th);
}

// ---------------------------------------------------------------------------
// K0: transpose+cast W1 -> W1t (bf16 [n][k]) and zero the stat shards.
// ---------------------------------------------------------------------------
__global__ void prep_kernel(const float* __restrict__ W1,
                            unsigned short* __restrict__ W1t,
                            float* __restrict__ stats /* 12288 f32 */)
{
    const int t = threadIdx.x, b = blockIdx.x;          // grid 256
    W1t[(size_t)t * DDIM + b] = f2bf(W1[(size_t)b * DDIM + t]);  // read coalesced
    if (b < 12) {
        float* s = stats + b * 1024;
        s[t] = 0.f; s[t + 256] = 0.f; s[t + 512] = 0.f; s[t + 768] = 0.f;
    }
}

// ---------------------------------------------------------------------------
// GEMM: out = GELU(A @ Wt^T + bias). A: [32768][256] bf16 (or gathered from
// fp32 table when GATHER). Wt: [256 n][256 k] bf16, read directly from
// global per-fragment. Block = 64 rows x 256 cols; wave wn owns cols
// wn*64..+63. Column sum/sumsq of the GELU output -> 8-way sharded global
// accumulators when DO_STATS.
// ---------------------------------------------------------------------------
template<int GATHER, int WRITE_F32, int DO_STATS>
__global__ __launch_bounds__(256, 2)
void gemm_enc(const unsigned short* __restrict__ A,
              const int* __restrict__ ids,
              const float* __restrict__ table,
              const unsigned short* __restrict__ Wt,
              const float* __restrict__ bias,
              void* __restrict__ outp,
              float* __restrict__ statShards /* this layer's 4096 f32 */)
{
    // A panel [64 r][32 granules of 8 bf16]; granule g of row r at slot
    // g^(r&7)  (validated R2/R4: frag reads ~conflict-free).
    __shared__ alignas(16) unsigned short Albs[64 * 256];    // 32768 B

    const int tid  = threadIdx.x;
    const int blk  = blockIdx.x;
    const int wave = tid >> 6;
    const int lane = tid & 63;
    const int quad = lane >> 4;
    const int l15  = lane & 15;
    const int wn   = wave;
    const int row0 = blk * 64;

    // ---- stage A panel once (thread t: row t>>2, 64-col chunk (t&3)*64) ----
    {
        const int r  = tid >> 2;
        const int c0 = (tid & 3) * 64;
        if (GATHER) {
            const int src = ids[row0 + r];
            const float* tp = table + (size_t)src * DDIM + c0;
#pragma unroll
            for (int j = 0; j < 8; ++j) {
                float4 v0 = *(const float4*)(tp + j * 8);
                float4 v1 = *(const float4*)(tp + j * 8 + 4);
                union { unsigned short u[8]; uint4 v; } o;
                o.u[0]=f2bf(v0.x); o.u[1]=f2bf(v0.y); o.u[2]=f2bf(v0.z); o.u[3]=f2bf(v0.w);
                o.u[4]=f2bf(v1.x); o.u[5]=f2bf(v1.y); o.u[6]=f2bf(v1.z); o.u[7]=f2bf(v1.w);
                const int g = (tid & 3) * 8 + j;
                *(uint4*)(Albs + r * 256 + (g ^ (r & 7)) * 8) = o.v;
            }
        } else {
            const unsigned short* ap = A + (size_t)(row0 + r) * DDIM + c0;
#pragma unroll
            for (int j = 0; j < 8; ++j) {
                uint4 v = *(const uint4*)(ap + j * 8);
                const int g = (tid & 3) * 8 + j;
                *(uint4*)(Albs + r * 256 + (g ^ (r & 7)) * 8) = v;
            }
        }
    }

    float bias_v[4];
#pragma unroll
    for (int nt = 0; nt < 4; ++nt)
        bias_v[nt] = bias[wn * 64 + nt * 16 + l15];

    floatx4 acc[4][4];
#pragma unroll
    for (int i = 0; i < 4; ++i)
#pragma unroll
        for (int j = 0; j < 4; ++j)
            acc[i][j] = floatx4{0.f, 0.f, 0.f, 0.f};

    __syncthreads();   // A panel visible to all waves (the ONLY barrier)

    // ---- K loop: B frags straight from global (L2-hot), A frags from LDS ----
    // B operand layout (R2-validated): lane holds Bt[n = nt*16+l15][k =
    // kk*32 + quad*8 .. +8], i.e. a 16B contiguous row chunk of Wt.
    const unsigned short* wb = Wt + (size_t)(wn * 64 + l15) * DDIM + quad * 8;
#pragma unroll 2
    for (int kk = 0; kk < 8; ++kk) {
        short8 bfr[4];
#pragma unroll
        for (int nt = 0; nt < 4; ++nt)
            bfr[nt] = *(const short8*)(wb + (size_t)(nt * 16) * DDIM + kk * 32);
        short8 af[4];
        const int agp = ((kk * 4 + quad) ^ (l15 & 7)) * 8;
#pragma unroll
        for (int mt = 0; mt < 4; ++mt)
            af[mt] = *(const short8*)(Albs + (mt * 16 + l15) * 256 + agp);
#pragma unroll
        for (int mt = 0; mt < 4; ++mt)
#pragma unroll
            for (int nt = 0; nt < 4; ++nt)
                acc[mt][nt] = __builtin_amdgcn_mfma_f32_16x16x32_bf16(
                    af[mt], bfr[nt], acc[mt][nt], 0, 0, 0);
    }

    // ---- epilogue: bias + GELU + store (+ sharded column stats) ----
    float s1[4] = {0.f, 0.f, 0.f, 0.f};
    float s2[4] = {0.f, 0.f, 0.f, 0.f};
#pragma unroll
    for (int mt = 0; mt < 4; ++mt) {
        const int rb = row0 + mt * 16 + quad * 4;            // C/D row=quad*4+reg
#pragma unroll
        for (int nt = 0; nt < 4; ++nt) {
            const int col = wn * 64 + nt * 16 + l15;         // C/D col=lane&15
#pragma unroll
            for (int i = 0; i < 4; ++i) {
                float y = gelu_fast(acc[mt][nt][i] + bias_v[nt]);
                if (WRITE_F32) {
                    ((float*)outp)[(size_t)(rb + i) * DDIM + col] = y;
                } else {
                    ((unsigned short*)outp)[(size_t)(rb + i) * DDIM + col] = f2bf(y);
                }
                if (DO_STATS) { s1[nt] += y; s2[nt] += y * y; }
            }
        }
    }
    if (DO_STATS) {
#pragma unroll
        for (int nt = 0; nt < 4; ++nt) {   // reduce the 4 quads (same column)
            s1[nt] += __shfl_xor(s1[nt], 16); s1[nt] += __shfl_xor(s1[nt], 32);
            s2[nt] += __shfl_xor(s2[nt], 16); s2[nt] += __shfl_xor(s2[nt], 32);
        }
        float* sb = statShards + (blk & 7) * 512;            // 8-way shard
        if (quad == 0) {
#pragma unroll
            for (int nt = 0; nt < 4; ++nt) {
                const int col = wn * 64 + nt * 16 + l15;
                atomicAdd(&sb[col],       s1[nt]);
                atomicAdd(&sb[256 + col], s2[nt]);
            }
        }
    }
}

// ---------------------------------------------------------------------------
// Fold: finalize sharded BN stats, fold affine into next layer's weights:
//   scale[k]=rsqrt(var+eps)*gamma[k]; shift[k]=beta[k]-mu[k]*scale[k]
//   Wt'[n][k]=scale[k]*W[k][n] (bf16);  b'[n]=b[n]+shift@W[:,n]
// ---------------------------------------------------------------------------
__global__ void fold_kernel(const float* __restrict__ shards,
                            const float* __restrict__ g,
                            const float* __restrict__ be,
                            const float* __restrict__ W,
                            const float* __restrict__ b,
                            unsigned short* __restrict__ Wt,
                            float* __restrict__ bOut)
{
    __shared__ float sc[256], sh[256], red[4];
    const int t = threadIdx.x;
    const int n = blockIdx.x;
    float sum = 0.f, sq = 0.f;
#pragma unroll
    for (int s = 0; s < 8; ++s) {
        sum += shards[s * 512 + t];
        sq  += shards[s * 512 + 256 + t];
    }
    const float mu  = sum * (1.0f / 32768.0f);
    const float var = sq * (1.0f / 32768.0f) - mu * mu;
    const float scale = rsqrtf(var + 1e-5f) * g[t];
    sc[t] = scale;
    sh[t] = be[t] - mu * scale;
    __syncthreads();
    const float w = W[t * DDIM + n];          // column n of W
    Wt[n * DDIM + t] = f2bf(sc[t] * w);
    float pp = sh[t] * w;
#pragma unroll
    for (int o = 32; o; o >>= 1) pp += __shfl_down(pp, o);
    if ((t & 63) == 0) red[t >> 6] = pp;
    __syncthreads();
    if (t == 0) bOut[n] = b[n] + red[0] + red[1] + red[2] + red[3];
}

// ---------------------------------------------------------------------------
extern "C" void kernel_launch(void* const* d_in, const int* in_sizes, int n_in,
                              void* d_out, int out_size, void* d_ws, size_t ws_size,
                              hipStream_t stream)
{
    const int*   ids   = (const int*)  d_in[0];
    const float* table = (const float*)d_in[1];
    const float* W1 = (const float*)d_in[2];  const float* b1 = (const float*)d_in[3];
    const float* W2 = (const float*)d_in[4];  const float* b2 = (const float*)d_in[5];
    const float* W3 = (const float*)d_in[6];  const float* b3 = (const float*)d_in[7];
    const float* W4 = (const float*)d_in[8];  const float* b4 = (const float*)d_in[9];
    const float* g1 = (const float*)d_in[10]; const float* be1 = (const float*)d_in[11];
    const float* g2 = (const float*)d_in[12]; const float* be2 = (const float*)d_in[13];
    const float* g3 = (const float*)d_in[14]; const float* be3 = (const float*)d_in[15];

    unsigned char* ws = (unsigned char*)d_ws;
    unsigned short* W1t = (unsigned short*)ws;                       // 128 KiB
    unsigned short* W2t = (unsigned short*)(ws + (size_t)131072);
    unsigned short* W3t = (unsigned short*)(ws + (size_t)262144);
    unsigned short* W4t = (unsigned short*)(ws + (size_t)393216);
    float* bb2   = (float*)(ws + (size_t)524288);
    float* bb3   = (float*)(ws + (size_t)525312);
    float* bb4   = (float*)(ws + (size_t)526336);
    float* stats = (float*)(ws + (size_t)527360);                    // 48 KiB
    unsigned short* act1 = (unsigned short*)(ws + (size_t)1048576);  // 16 MiB
    unsigned short* act2 = (unsigned short*)(ws + (size_t)17825792); // 16 MiB

    prep_kernel<<<256, 256, 0, stream>>>(W1, W1t, stats);

    gemm_enc<1, 0, 1><<<512, 256, 0, stream>>>(nullptr, ids, table, W1t, b1,
                                               act1, stats);
    fold_kernel<<<256, 256, 0, stream>>>(stats, g1, be1, W2, b2, W2t, bb2);

    gemm_enc<0, 0, 1><<<512, 256, 0, stream>>>(act1, nullptr, nullptr, W2t, bb2,
                                               act2, stats + 4096);
    fold_kernel<<<256, 256, 0, stream>>>(stats + 4096, g2, be2, W3, b3, W3t, bb3);

    gemm_enc<0, 0, 1><<<512, 256, 0, stream>>>(act2, nullptr, nullptr, W3t, bb3,
                                               act1, stats + 8192);
    fold_kernel<<<256, 256, 0, stream>>>(stats + 8192, g3, be3, W4, b4, W4t, bb4);

    gemm_enc<0, 1, 0><<<512, 256, 0, stream>>>(act1, nullptr, nullptr, W4t, bb4,
                                               (void*)d_out, nullptr);
}